// Round 2
// baseline (1377.770 us; speedup 1.0000x reference)
//
#include <hip/hip_runtime.h>
#include <hip/hip_bf16.h>

// DCNv2 R2: bf16 MFMA for the main einsum.
//   k_transpose: x NCHW f32 -> NHWC bf16 (xtu, uint-packed pairs)
//   k_prep:      wtu[o][n*128+c] bf16 pairs; offwt[c][kyx][27] f32
//   k_offconv:   offset/mask conv, 1024 blocks, c-split x4 + LDS reduce, mask pre-sigmoided
//   k_fused:     per (b,ho) row: sample S[64px][128c] bf16 into swizzled LDS per tap,
//                D[o][px] = W*S^T via v_mfma_f32_16x16x32_bf16 (A=W so stores are px-contiguous)

typedef unsigned int u32;
typedef __attribute__((ext_vector_type(8))) short bf16x8;
typedef __attribute__((ext_vector_type(4))) float f32x4;

union U16 { uint4 u; bf16x8 h; };

static __device__ __forceinline__ float blo(u32 u) { return __uint_as_float(u << 16); }
static __device__ __forceinline__ float bhi(u32 u) { return __uint_as_float(u & 0xFFFF0000u); }
static __device__ __forceinline__ u32 pk(float a, float b) {
    __hip_bfloat162 h = __float22bfloat162_rn(make_float2(a, b));
    union { __hip_bfloat162 h2; u32 u; } c; c.h2 = h; return c.u;
}

#define B_   16
#define HW_  4096
#define CU_  64          // 128 ch = 64 uint pairs

// ---------------- kernel 1: NCHW f32 -> NHWC bf16 ----------------
__global__ __launch_bounds__(256) void k_transpose(const float* __restrict__ x,
                                                   u32* __restrict__ xtu) {
    __shared__ float tile[32][129];
    int blk = blockIdx.x, t = threadIdx.x;
    int b = blk >> 7, hw0 = (blk & 127) << 5;
    int hwl = t & 31, cg = t >> 5;
    const float* src = x + (size_t)b * 128 * HW_ + hw0 + hwl;
#pragma unroll
    for (int i = 0; i < 16; ++i) { int c = cg + (i << 3); tile[hwl][c] = src[(size_t)c * HW_]; }
    __syncthreads();
    u32* dst = xtu + ((size_t)b * HW_ + hw0) * CU_;
    int u = t & 63, hq = t >> 6;
#pragma unroll
    for (int j = 0; j < 8; ++j) {
        int hw = (hq << 3) + j;
        dst[(size_t)hw * CU_ + u] = pk(tile[hw][2 * u], tile[hw][2 * u + 1]);
    }
}

// ---------------- kernel 2: weight prep ----------------
// wtu: [o][576]  uint pair idx = n*64 + c/2, value = bf16(weight[o][c][n]) pair
// offwt: [c][kyx][27] f32
__global__ __launch_bounds__(256) void k_prep(const float* __restrict__ weight,
                                              const float* __restrict__ off_w,
                                              u32* __restrict__ wtu,
                                              float* __restrict__ offwt) {
    int idx = blockIdx.x * 256 + threadIdx.x;
    if (idx < 73728) {
        int o = idx / 576, r = idx % 576;
        int n = r / 64, cu = r % 64, c = cu * 2;
        float a = weight[((size_t)(o * 128 + c)) * 9 + n];
        float b = weight[((size_t)(o * 128 + c + 1)) * 9 + n];
        wtu[idx] = pk(a, b);
    } else {
        int k = idx - 73728;
        if (k < 31104) {
            int c = k / 243, r2 = k % 243;
            int kyx = r2 / 27, ch = r2 % 27;
            offwt[k] = off_w[((size_t)(ch * 128 + c)) * 9 + kyx];
        }
    }
}

// ---------------- kernel 3: offset/mask conv ----------------
__global__ __launch_bounds__(256) void k_offconv(const u32* __restrict__ xtu,
                                                 const float* __restrict__ offwt,
                                                 const float* __restrict__ off_b,
                                                 float* __restrict__ offout) {
    __shared__ float red[4][64][29];
    int blk = blockIdx.x, t = threadIdx.x;
    int b = blk >> 6, ho = blk & 63;
    int px = t & 63, cq = t >> 6;
    float acc[27];
#pragma unroll
    for (int ch = 0; ch < 27; ++ch) acc[ch] = 0.f;
    const u32* xb = xtu + (size_t)b * HW_ * CU_;
#pragma unroll 1
    for (int tap = 0; tap < 9; ++tap) {
        int ky = tap / 3, kx = tap % 3;
        int yy = ho + ky - 1, xx = px + kx - 1;
        bool v = ((unsigned)yy < 64u) && ((unsigned)xx < 64u);
        const u32* src = xb + (yy * 64 + xx) * CU_ + cq * 16;
        uint4 z = {0u, 0u, 0u, 0u};
#pragma unroll
        for (int k = 0; k < 4; ++k) {
            uint4 q = v ? *(const uint4*)(src + k * 4) : z;
            u32 qa[4] = {q.x, q.y, q.z, q.w};
#pragma unroll
            for (int e = 0; e < 4; ++e) {
                int c = cq * 32 + k * 8 + e * 2;
                float f0 = blo(qa[e]), f1 = bhi(qa[e]);
                const float* wr0 = offwt + ((size_t)c * 9 + tap) * 27;
                const float* wr1 = wr0 + 243;
#pragma unroll
                for (int ch = 0; ch < 27; ++ch) acc[ch] += f0 * wr0[ch] + f1 * wr1[ch];
            }
        }
    }
#pragma unroll
    for (int ch = 0; ch < 27; ++ch) red[cq][px][ch] = acc[ch];
    __syncthreads();
    int q2 = t >> 6, ch0 = q2 * 7, nch = (q2 == 3) ? 6 : 7;
    float* dst = offout + (size_t)b * 27 * HW_ + ho * 64 + px;
    for (int i = 0; i < nch; ++i) {
        int ch = ch0 + i;
        float s = red[0][px][ch] + red[1][px][ch] + red[2][px][ch] + red[3][px][ch] + off_b[ch];
        if (ch >= 18) s = 1.f / (1.f + __expf(-s));
        dst[(size_t)ch * HW_] = s;
    }
}

// ---------------- kernel 4: fused bilinear sample + MFMA einsum ----------------
__global__ __launch_bounds__(256) void k_fused(const u32* __restrict__ xtu,
                                               const float* __restrict__ offout,
                                               const u32* __restrict__ wtu,
                                               const float* __restrict__ bias,
                                               float* __restrict__ out) {
    __shared__ __align__(16) u32 S[64][64];   // [px][bf16-pair], chunk-XOR swizzled, 16 KB
    int blk = blockIdx.x, t = threadIdx.x;
    int b = blk >> 6, ho = blk & 63;
    int p = t & 63, cq = t >> 6;
    int w = t >> 6, lane = t & 63, l15 = lane & 15, lhi = lane >> 4;
    int o0 = w * 32;

    f32x4 acc[2][4];
#pragma unroll
    for (int ob = 0; ob < 2; ++ob)
#pragma unroll
        for (int pb = 0; pb < 4; ++pb) acc[ob][pb] = (f32x4){0.f, 0.f, 0.f, 0.f};

    const float* offb = offout + (size_t)b * 27 * HW_ + ho * 64 + p;
    const u32* xb = xtu + (size_t)b * HW_ * CU_;

#pragma unroll 1
    for (int n = 0; n < 9; ++n) {
        // --- preload W fragments for this tap (L2-resident; hides under sampling) ---
        uint4 wf[2][4];
#pragma unroll
        for (int ob = 0; ob < 2; ++ob)
#pragma unroll
            for (int ks = 0; ks < 4; ++ks)
                wf[ob][ks] = *(const uint4*)(wtu + (size_t)(o0 + ob * 16 + l15) * 576
                                             + n * 64 + ks * 16 + lhi * 4);
        // --- bilinear sample tap n into S (bf16, swizzled) ---
        float dy = offb[(size_t)(2 * n) * HW_];
        float dx = offb[(size_t)(2 * n + 1) * HW_];
        float m  = offb[(size_t)(18 + n) * HW_];
        float ys = (float)(ho + n / 3 - 1) + dy;
        float xs = (float)(p + n % 3 - 1) + dx;
        float y0f = floorf(ys), x0f = floorf(xs);
        float fy = ys - y0f, fx = xs - x0f;
        int y0 = (int)y0f, x0 = (int)x0f;
        float w00 = (1.f - fy) * (1.f - fx) * m;
        float w01 = (1.f - fy) * fx * m;
        float w10 = fy * (1.f - fx) * m;
        float w11 = fy * fx * m;
        bool vy0 = (unsigned)y0 < 64u, vy1 = (unsigned)(y0 + 1) < 64u;
        bool vx0 = (unsigned)x0 < 64u, vx1 = (unsigned)(x0 + 1) < 64u;
        bool v00 = vy0 && vx0, v01 = vy0 && vx1, v10 = vy1 && vx0, v11 = vy1 && vx1;
        int i00 = (y0 * 64 + x0) * CU_ + cq * 16;
        uint4 z = {0u, 0u, 0u, 0u};
#pragma unroll
        for (int k = 0; k < 4; ++k) {
            uint4 a  = v00 ? *(const uint4*)(xb + i00 + k * 4) : z;
            uint4 bq = v01 ? *(const uint4*)(xb + i00 + CU_ + k * 4) : z;
            uint4 c  = v10 ? *(const uint4*)(xb + i00 + 64 * CU_ + k * 4) : z;
            uint4 d  = v11 ? *(const uint4*)(xb + i00 + 64 * CU_ + CU_ + k * 4) : z;
            u32 aa[4] = {a.x, a.y, a.z, a.w};
            u32 ba[4] = {bq.x, bq.y, bq.z, bq.w};
            u32 ca[4] = {c.x, c.y, c.z, c.w};
            u32 da[4] = {d.x, d.y, d.z, d.w};
            u32 r[4];
#pragma unroll
            for (int e = 0; e < 4; ++e) {
                float slo = w00 * blo(aa[e]) + w01 * blo(ba[e]) + w10 * blo(ca[e]) + w11 * blo(da[e]);
                float shi = w00 * bhi(aa[e]) + w01 * bhi(ba[e]) + w10 * bhi(ca[e]) + w11 * bhi(da[e]);
                r[e] = pk(slo, shi);
            }
            uint4 rv = {r[0], r[1], r[2], r[3]};
            *(uint4*)&S[p][(((cq << 2) + k) ^ (p & 7)) << 2] = rv;
        }
        __syncthreads();
        // --- MFMA: D[o][px] += W_tap * S_tap^T ---
#pragma unroll
        for (int ks = 0; ks < 4; ++ks) {
            U16 sf[4];
#pragma unroll
            for (int pb = 0; pb < 4; ++pb) {
                int pr = pb * 16 + l15;
                sf[pb].u = *(const uint4*)&S[pr][((ks * 4 + lhi) ^ (pr & 7)) << 2];
            }
#pragma unroll
            for (int ob = 0; ob < 2; ++ob) {
                U16 af; af.u = wf[ob][ks];
#pragma unroll
                for (int pb = 0; pb < 4; ++pb)
                    acc[ob][pb] = __builtin_amdgcn_mfma_f32_16x16x32_bf16(
                        af.h, sf[pb].h, acc[ob][pb], 0, 0, 0);
            }
        }
        __syncthreads();
    }
    // --- epilogue: row o = o0+ob*16+lhi*4+r, col px = pb*16+l15 ---
    float* ob_base = out + (size_t)b * 128 * HW_ + ho * 64;
#pragma unroll
    for (int ob = 0; ob < 2; ++ob)
#pragma unroll
        for (int r = 0; r < 4; ++r) {
            int o = o0 + ob * 16 + lhi * 4 + r;
            float bv = bias[o];
#pragma unroll
            for (int pb = 0; pb < 4; ++pb)
                ob_base[(size_t)o * HW_ + pb * 16 + l15] = acc[ob][pb][r] + bv;
        }
}

extern "C" void kernel_launch(void* const* d_in, const int* in_sizes, int n_in,
                              void* d_out, int out_size, void* d_ws, size_t ws_size,
                              hipStream_t stream) {
    const float* x      = (const float*)d_in[0];
    const float* weight = (const float*)d_in[1];
    const float* bias   = (const float*)d_in[2];
    const float* off_w  = (const float*)d_in[3];
    const float* off_b  = (const float*)d_in[4];
    float* out = (float*)d_out;

    // ws: xtu (16 MB) | offout (7.1 MB) | wtu (288 KB) | offwt (122 KB)
    u32*   xtu    = (u32*)d_ws;
    float* offout = (float*)(xtu + (size_t)B_ * HW_ * CU_);
    u32*   wtu    = (u32*)(offout + (size_t)B_ * 27 * HW_);
    float* offwt  = (float*)(wtu + 73728);

    hipLaunchKernelGGL(k_transpose, dim3(2048), dim3(256), 0, stream, x, xtu);
    hipLaunchKernelGGL(k_prep, dim3((73728 + 31104 + 255) / 256), dim3(256), 0, stream,
                       weight, off_w, wtu, offwt);
    hipLaunchKernelGGL(k_offconv, dim3(1024), dim3(256), 0, stream, xtu, offwt, off_b, offout);
    hipLaunchKernelGGL(k_fused, dim3(1024), dim3(256), 0, stream, xtu, offout, wtu, bias, out);
}

// Round 3
// 358.328 us; speedup vs baseline: 3.8450x; 3.8450x over previous
//
#include <hip/hip_runtime.h>
#include <hip/hip_bf16.h>

// DCNv2 R3: both convs on MFMA.
//   k_transpose: x NCHW f32 -> NHWC bf16 (xtu, uint-packed pairs)
//   k_prep:      wtu[o][n*64+cu] bf16 pairs; woffu[32(pad27)][tap*64+cu] bf16 pairs
//   k_offconv:   offset/mask conv as MFMA GEMM: stage rows ho-1..ho+1 in swizzled LDS once,
//                9 taps = shifted B-fragment reads; M=32(pad), mask pre-sigmoided
//   k_fused:     unchanged from R2 (validated): per-tap bilinear sample into swizzled LDS,
//                D[o][px] = W*S^T via v_mfma_f32_16x16x32_bf16

typedef unsigned int u32;
typedef __attribute__((ext_vector_type(8))) short bf16x8;
typedef __attribute__((ext_vector_type(4))) float f32x4;

union U16 { uint4 u; bf16x8 h; };

static __device__ __forceinline__ float blo(u32 u) { return __uint_as_float(u << 16); }
static __device__ __forceinline__ float bhi(u32 u) { return __uint_as_float(u & 0xFFFF0000u); }
static __device__ __forceinline__ u32 pk(float a, float b) {
    __hip_bfloat162 h = __float22bfloat162_rn(make_float2(a, b));
    union { __hip_bfloat162 h2; u32 u; } c; c.h2 = h; return c.u;
}

#define B_   16
#define HW_  4096
#define CU_  64          // 128 ch = 64 uint pairs

// ---------------- kernel 1: NCHW f32 -> NHWC bf16 ----------------
__global__ __launch_bounds__(256) void k_transpose(const float* __restrict__ x,
                                                   u32* __restrict__ xtu) {
    __shared__ float tile[32][129];
    int blk = blockIdx.x, t = threadIdx.x;
    int b = blk >> 7, hw0 = (blk & 127) << 5;
    int hwl = t & 31, cg = t >> 5;
    const float* src = x + (size_t)b * 128 * HW_ + hw0 + hwl;
#pragma unroll
    for (int i = 0; i < 16; ++i) { int c = cg + (i << 3); tile[hwl][c] = src[(size_t)c * HW_]; }
    __syncthreads();
    u32* dst = xtu + ((size_t)b * HW_ + hw0) * CU_;
    int u = t & 63, hq = t >> 6;
#pragma unroll
    for (int j = 0; j < 8; ++j) {
        int hw = (hq << 3) + j;
        dst[(size_t)hw * CU_ + u] = pk(tile[hw][2 * u], tile[hw][2 * u + 1]);
    }
}

// ---------------- kernel 2: weight prep ----------------
// wtu:   [o][576]   pair idx = n*64 + cu,  bf16(weight[o][2cu..2cu+1][n])
// woffu: [32][576]  pair idx = tap*64+cu,  bf16(off_w[o][2cu..][tap]); rows 27..31 zero
__global__ __launch_bounds__(256) void k_prep(const float* __restrict__ weight,
                                              const float* __restrict__ off_w,
                                              u32* __restrict__ wtu,
                                              u32* __restrict__ woffu) {
    int idx = blockIdx.x * 256 + threadIdx.x;
    if (idx < 73728) {
        int o = idx / 576, r = idx % 576;
        int n = r / 64, cu = r % 64, c = cu * 2;
        float a = weight[((size_t)(o * 128 + c)) * 9 + n];
        float b = weight[((size_t)(o * 128 + c + 1)) * 9 + n];
        wtu[idx] = pk(a, b);
    } else if (idx < 73728 + 18432) {
        int k = idx - 73728;
        int o = k / 576, r = k % 576;
        int tap = r / 64, cu = r % 64, c = cu * 2;
        u32 v = 0u;
        if (o < 27) {
            float a = off_w[((size_t)(o * 128 + c)) * 9 + tap];
            float b = off_w[((size_t)(o * 128 + c + 1)) * 9 + tap];
            v = pk(a, b);
        }
        woffu[k] = v;
    }
}

// ---------------- kernel 3: offset/mask conv via MFMA ----------------
__global__ __launch_bounds__(256) void k_offconv(const u32* __restrict__ xtu,
                                                 const u32* __restrict__ woffu,
                                                 const float* __restrict__ off_b,
                                                 float* __restrict__ offout) {
    __shared__ __align__(16) u32 S[3][64][64];   // rows ho-1..ho+1, swizzled, 48 KB
    int blk = blockIdx.x, t = threadIdx.x;
    int b = blk >> 6, ho = blk & 63;
    const u32* xb = xtu + (size_t)b * HW_ * CU_;
    const uint4 z4 = {0u, 0u, 0u, 0u};
    // stage 3 rows (3072 uint4, 12 per thread)
#pragma unroll
    for (int i = 0; i < 12; ++i) {
        int li = t + (i << 8);
        int r = li >> 10, rem = li & 1023;
        int px = rem >> 4, ch = rem & 15;
        int yy = ho + r - 1;
        uint4 v = ((unsigned)yy < 64u) ? *(const uint4*)(xb + ((yy << 6) + px) * CU_ + (ch << 2)) : z4;
        *(uint4*)&S[r][px][(ch ^ (px & 7)) << 2] = v;
    }
    __syncthreads();
    int lane = t & 63, w = t >> 6, l15 = lane & 15, lhi = lane >> 4;
    int ob = w >> 1, pb0 = (w & 1) << 1;
    f32x4 acc[2];
    acc[0] = (f32x4){0.f, 0.f, 0.f, 0.f};
    acc[1] = (f32x4){0.f, 0.f, 0.f, 0.f};
#pragma unroll 1
    for (int tap = 0; tap < 9; ++tap) {
        int ky = tap / 3, kx = tap % 3;
        int yy = ho + ky - 1;
        if ((unsigned)yy >= 64u) continue;
        U16 af[4];
#pragma unroll
        for (int ks = 0; ks < 4; ++ks)
            af[ks].u = *(const uint4*)(woffu + (size_t)(ob * 16 + l15) * 576
                                       + tap * 64 + ks * 16 + lhi * 4);
#pragma unroll
        for (int pp = 0; pp < 2; ++pp) {
            int pr = ((pb0 + pp) << 4) + l15;
            int pxs = pr + kx - 1;
            bool v = (unsigned)pxs < 64u;
            int pxc = v ? pxs : 0;
#pragma unroll
            for (int ks = 0; ks < 4; ++ks) {
                U16 sf;
                sf.u = v ? *(const uint4*)&S[ky][pxc][((ks * 4 + lhi) ^ (pxc & 7)) << 2] : z4;
                acc[pp] = __builtin_amdgcn_mfma_f32_16x16x32_bf16(af[ks].h, sf.h, acc[pp], 0, 0, 0);
            }
        }
    }
    // epilogue: o = ob*16+lhi*4+r, px = (pb0+pp)*16+l15 ; only o<27 real
    float* dst = offout + (size_t)b * 27 * HW_ + (ho << 6);
#pragma unroll
    for (int pp = 0; pp < 2; ++pp)
#pragma unroll
        for (int r = 0; r < 4; ++r) {
            int o = ob * 16 + lhi * 4 + r;
            if (o < 27) {
                float s = acc[pp][r] + off_b[o];
                if (o >= 18) s = 1.f / (1.f + __expf(-s));
                dst[(size_t)o * HW_ + ((pb0 + pp) << 4) + l15] = s;
            }
        }
}

// ---------------- kernel 4: fused bilinear sample + MFMA einsum ----------------
__global__ __launch_bounds__(256) void k_fused(const u32* __restrict__ xtu,
                                               const float* __restrict__ offout,
                                               const u32* __restrict__ wtu,
                                               const float* __restrict__ bias,
                                               float* __restrict__ out) {
    __shared__ __align__(16) u32 S[64][64];   // [px][bf16-pair], chunk-XOR swizzled, 16 KB
    int blk = blockIdx.x, t = threadIdx.x;
    int b = blk >> 6, ho = blk & 63;
    int p = t & 63, cq = t >> 6;
    int w = t >> 6, lane = t & 63, l15 = lane & 15, lhi = lane >> 4;
    int o0 = w * 32;

    f32x4 acc[2][4];
#pragma unroll
    for (int ob = 0; ob < 2; ++ob)
#pragma unroll
        for (int pb = 0; pb < 4; ++pb) acc[ob][pb] = (f32x4){0.f, 0.f, 0.f, 0.f};

    const float* offb = offout + (size_t)b * 27 * HW_ + ho * 64 + p;
    const u32* xb = xtu + (size_t)b * HW_ * CU_;

#pragma unroll 1
    for (int n = 0; n < 9; ++n) {
        // --- preload W fragments for this tap (L2-resident; hides under sampling) ---
        uint4 wf[2][4];
#pragma unroll
        for (int ob = 0; ob < 2; ++ob)
#pragma unroll
            for (int ks = 0; ks < 4; ++ks)
                wf[ob][ks] = *(const uint4*)(wtu + (size_t)(o0 + ob * 16 + l15) * 576
                                             + n * 64 + ks * 16 + lhi * 4);
        // --- bilinear sample tap n into S (bf16, swizzled) ---
        float dy = offb[(size_t)(2 * n) * HW_];
        float dx = offb[(size_t)(2 * n + 1) * HW_];
        float m  = offb[(size_t)(18 + n) * HW_];
        float ys = (float)(ho + n / 3 - 1) + dy;
        float xs = (float)(p + n % 3 - 1) + dx;
        float y0f = floorf(ys), x0f = floorf(xs);
        float fy = ys - y0f, fx = xs - x0f;
        int y0 = (int)y0f, x0 = (int)x0f;
        float w00 = (1.f - fy) * (1.f - fx) * m;
        float w01 = (1.f - fy) * fx * m;
        float w10 = fy * (1.f - fx) * m;
        float w11 = fy * fx * m;
        bool vy0 = (unsigned)y0 < 64u, vy1 = (unsigned)(y0 + 1) < 64u;
        bool vx0 = (unsigned)x0 < 64u, vx1 = (unsigned)(x0 + 1) < 64u;
        bool v00 = vy0 && vx0, v01 = vy0 && vx1, v10 = vy1 && vx0, v11 = vy1 && vx1;
        int i00 = (y0 * 64 + x0) * CU_ + cq * 16;
        uint4 z = {0u, 0u, 0u, 0u};
#pragma unroll
        for (int k = 0; k < 4; ++k) {
            uint4 a  = v00 ? *(const uint4*)(xb + i00 + k * 4) : z;
            uint4 bq = v01 ? *(const uint4*)(xb + i00 + CU_ + k * 4) : z;
            uint4 c  = v10 ? *(const uint4*)(xb + i00 + 64 * CU_ + k * 4) : z;
            uint4 d  = v11 ? *(const uint4*)(xb + i00 + 64 * CU_ + CU_ + k * 4) : z;
            u32 aa[4] = {a.x, a.y, a.z, a.w};
            u32 ba[4] = {bq.x, bq.y, bq.z, bq.w};
            u32 ca[4] = {c.x, c.y, c.z, c.w};
            u32 da[4] = {d.x, d.y, d.z, d.w};
            u32 r[4];
#pragma unroll
            for (int e = 0; e < 4; ++e) {
                float slo = w00 * blo(aa[e]) + w01 * blo(ba[e]) + w10 * blo(ca[e]) + w11 * blo(da[e]);
                float shi = w00 * bhi(aa[e]) + w01 * bhi(ba[e]) + w10 * bhi(ca[e]) + w11 * bhi(da[e]);
                r[e] = pk(slo, shi);
            }
            uint4 rv = {r[0], r[1], r[2], r[3]};
            *(uint4*)&S[p][(((cq << 2) + k) ^ (p & 7)) << 2] = rv;
        }
        __syncthreads();
        // --- MFMA: D[o][px] += W_tap * S_tap^T ---
#pragma unroll
        for (int ks = 0; ks < 4; ++ks) {
            U16 sf[4];
#pragma unroll
            for (int pb = 0; pb < 4; ++pb) {
                int pr = pb * 16 + l15;
                sf[pb].u = *(const uint4*)&S[pr][((ks * 4 + lhi) ^ (pr & 7)) << 2];
            }
#pragma unroll
            for (int ob = 0; ob < 2; ++ob) {
                U16 af; af.u = wf[ob][ks];
#pragma unroll
                for (int pb = 0; pb < 4; ++pb)
                    acc[ob][pb] = __builtin_amdgcn_mfma_f32_16x16x32_bf16(
                        af.h, sf[pb].h, acc[ob][pb], 0, 0, 0);
            }
        }
        __syncthreads();
    }
    // --- epilogue: row o = o0+ob*16+lhi*4+r, col px = pb*16+l15 ---
    float* ob_base = out + (size_t)b * 128 * HW_ + ho * 64;
#pragma unroll
    for (int ob = 0; ob < 2; ++ob)
#pragma unroll
        for (int r = 0; r < 4; ++r) {
            int o = o0 + ob * 16 + lhi * 4 + r;
            float bv = bias[o];
#pragma unroll
            for (int pb = 0; pb < 4; ++pb)
                ob_base[(size_t)o * HW_ + pb * 16 + l15] = acc[ob][pb][r] + bv;
        }
}

extern "C" void kernel_launch(void* const* d_in, const int* in_sizes, int n_in,
                              void* d_out, int out_size, void* d_ws, size_t ws_size,
                              hipStream_t stream) {
    const float* x      = (const float*)d_in[0];
    const float* weight = (const float*)d_in[1];
    const float* bias   = (const float*)d_in[2];
    const float* off_w  = (const float*)d_in[3];
    const float* off_b  = (const float*)d_in[4];
    float* out = (float*)d_out;

    // ws: xtu (16 MB) | offout (7.1 MB) | wtu (288 KB) | woffu (72 KB)
    u32*   xtu    = (u32*)d_ws;
    float* offout = (float*)(xtu + (size_t)B_ * HW_ * CU_);
    u32*   wtu    = (u32*)(offout + (size_t)B_ * 27 * HW_);
    u32*   woffu  = wtu + 73728;

    hipLaunchKernelGGL(k_transpose, dim3(2048), dim3(256), 0, stream, x, xtu);
    hipLaunchKernelGGL(k_prep, dim3((73728 + 18432 + 255) / 256), dim3(256), 0, stream,
                       weight, off_w, wtu, woffu);
    hipLaunchKernelGGL(k_offconv, dim3(1024), dim3(256), 0, stream, xtu, woffu, off_b, offout);
    hipLaunchKernelGGL(k_fused, dim3(1024), dim3(256), 0, stream, xtu, offout, wtu, bias, out);
}

// Round 4
// 130.760 us; speedup vs baseline: 10.5366x; 2.7403x over previous
//
#include <hip/hip_runtime.h>
#include <hip/hip_bf16.h>

// DCNv2 R4: coalesced channel-major gather in k_fused.
//   k_fused per tap: A) each lane computes params (4 masked weights, 4 clamped
//   base addrs) for pixel (w*16 + lane&15); B) per px jj: v_readlane broadcasts
//   params to SGPRs, 4 coalesced global_load_dword (lane=channel-pair), blend,
//   write S[buf][px][lane]; one __syncthreads; C) MFMA D[o][px] += W*S^T.
//   S double-buffered, rows padded to 68 words (conflict-free canonical b128).
//   XCD-chunked block swizzle: each XCD works on 2 batches (4MB = its L2).

typedef unsigned int u32;
typedef __attribute__((ext_vector_type(8))) short bf16x8;
typedef __attribute__((ext_vector_type(4))) float f32x4;

union U16 { uint4 u; bf16x8 h; };

static __device__ __forceinline__ float blo(u32 u) { return __uint_as_float(u << 16); }
static __device__ __forceinline__ float bhi(u32 u) { return __uint_as_float(u & 0xFFFF0000u); }
static __device__ __forceinline__ u32 pk(float a, float b) {
    __hip_bfloat162 h = __float22bfloat162_rn(make_float2(a, b));
    union { __hip_bfloat162 h2; u32 u; } c; c.h2 = h; return c.u;
}
static __device__ __forceinline__ float rlf(float v, int l) {
    return __uint_as_float((u32)__builtin_amdgcn_readlane((int)__float_as_uint(v), l));
}

#define B_   16
#define HW_  4096
#define CU_  64          // 128 ch = 64 uint pairs

// ---------------- kernel 1: NCHW f32 -> NHWC bf16 ----------------
__global__ __launch_bounds__(256) void k_transpose(const float* __restrict__ x,
                                                   u32* __restrict__ xtu) {
    __shared__ float tile[32][129];
    int blk = blockIdx.x, t = threadIdx.x;
    int b = blk >> 7, hw0 = (blk & 127) << 5;
    int hwl = t & 31, cg = t >> 5;
    const float* src = x + (size_t)b * 128 * HW_ + hw0 + hwl;
#pragma unroll
    for (int i = 0; i < 16; ++i) { int c = cg + (i << 3); tile[hwl][c] = src[(size_t)c * HW_]; }
    __syncthreads();
    u32* dst = xtu + ((size_t)b * HW_ + hw0) * CU_;
    int u = t & 63, hq = t >> 6;
#pragma unroll
    for (int j = 0; j < 8; ++j) {
        int hw = (hq << 3) + j;
        dst[(size_t)hw * CU_ + u] = pk(tile[hw][2 * u], tile[hw][2 * u + 1]);
    }
}

// ---------------- kernel 2: weight prep ----------------
__global__ __launch_bounds__(256) void k_prep(const float* __restrict__ weight,
                                              const float* __restrict__ off_w,
                                              u32* __restrict__ wtu,
                                              u32* __restrict__ woffu) {
    int idx = blockIdx.x * 256 + threadIdx.x;
    if (idx < 73728) {
        int o = idx / 576, r = idx % 576;
        int n = r / 64, cu = r % 64, c = cu * 2;
        float a = weight[((size_t)(o * 128 + c)) * 9 + n];
        float b = weight[((size_t)(o * 128 + c + 1)) * 9 + n];
        wtu[idx] = pk(a, b);
    } else if (idx < 73728 + 18432) {
        int k = idx - 73728;
        int o = k / 576, r = k % 576;
        int tap = r / 64, cu = r % 64, c = cu * 2;
        u32 v = 0u;
        if (o < 27) {
            float a = off_w[((size_t)(o * 128 + c)) * 9 + tap];
            float b = off_w[((size_t)(o * 128 + c + 1)) * 9 + tap];
            v = pk(a, b);
        }
        woffu[k] = v;
    }
}

// ---------------- kernel 3: offset/mask conv via MFMA ----------------
__global__ __launch_bounds__(256) void k_offconv(const u32* __restrict__ xtu,
                                                 const u32* __restrict__ woffu,
                                                 const float* __restrict__ off_b,
                                                 float* __restrict__ offout) {
    __shared__ __align__(16) u32 S[3][64][64];
    int blk = ((blockIdx.x & 7) << 7) + (blockIdx.x >> 3);   // XCD-chunked
    int t = threadIdx.x;
    int b = blk >> 6, ho = blk & 63;
    const u32* xb = xtu + (size_t)b * HW_ * CU_;
    const uint4 z4 = {0u, 0u, 0u, 0u};
#pragma unroll
    for (int i = 0; i < 12; ++i) {
        int li = t + (i << 8);
        int r = li >> 10, rem = li & 1023;
        int px = rem >> 4, ch = rem & 15;
        int yy = ho + r - 1;
        uint4 v = ((unsigned)yy < 64u) ? *(const uint4*)(xb + ((yy << 6) + px) * CU_ + (ch << 2)) : z4;
        *(uint4*)&S[r][px][(ch ^ (px & 7)) << 2] = v;
    }
    __syncthreads();
    int lane = t & 63, w = t >> 6, l15 = lane & 15, lhi = lane >> 4;
    int ob = w >> 1, pb0 = (w & 1) << 1;
    f32x4 acc[2];
    acc[0] = (f32x4){0.f, 0.f, 0.f, 0.f};
    acc[1] = (f32x4){0.f, 0.f, 0.f, 0.f};
#pragma unroll 1
    for (int tap = 0; tap < 9; ++tap) {
        int ky = tap / 3, kx = tap % 3;
        int yy = ho + ky - 1;
        if ((unsigned)yy >= 64u) continue;
        U16 af[4];
#pragma unroll
        for (int ks = 0; ks < 4; ++ks)
            af[ks].u = *(const uint4*)(woffu + (size_t)(ob * 16 + l15) * 576
                                       + tap * 64 + ks * 16 + lhi * 4);
#pragma unroll
        for (int pp = 0; pp < 2; ++pp) {
            int pr = ((pb0 + pp) << 4) + l15;
            int pxs = pr + kx - 1;
            bool v = (unsigned)pxs < 64u;
            int pxc = v ? pxs : 0;
#pragma unroll
            for (int ks = 0; ks < 4; ++ks) {
                U16 sf;
                sf.u = v ? *(const uint4*)&S[ky][pxc][((ks * 4 + lhi) ^ (pxc & 7)) << 2] : z4;
                acc[pp] = __builtin_amdgcn_mfma_f32_16x16x32_bf16(af[ks].h, sf.h, acc[pp], 0, 0, 0);
            }
        }
    }
    float* dst = offout + (size_t)b * 27 * HW_ + (ho << 6);
#pragma unroll
    for (int pp = 0; pp < 2; ++pp)
#pragma unroll
        for (int r = 0; r < 4; ++r) {
            int o = ob * 16 + lhi * 4 + r;
            if (o < 27) {
                float s = acc[pp][r] + off_b[o];
                if (o >= 18) s = 1.f / (1.f + __expf(-s));
                dst[(size_t)o * HW_ + ((pb0 + pp) << 4) + l15] = s;
            }
        }
}

// ---------------- kernel 4: fused sample + MFMA, coalesced gather ----------------
__global__ __launch_bounds__(256, 4) void k_fused(const u32* __restrict__ xtu,
                                                  const float* __restrict__ offout,
                                                  const u32* __restrict__ wtu,
                                                  const float* __restrict__ bias,
                                                  float* __restrict__ out) {
    __shared__ __align__(16) u32 S[2][64][68];   // dbuf, 68-word rows, 34.8 KB
    int blk = ((blockIdx.x & 7) << 7) + (blockIdx.x >> 3);   // XCD-chunked
    int t = threadIdx.x;
    int b = blk >> 6, ho = blk & 63;
    int w = t >> 6, lane = t & 63, l15 = lane & 15, lhi = lane >> 4;
    int o0 = w * 32;
    int pxa = (w << 4) + l15;        // pixel this lane computes params for

    f32x4 acc[2][4];
#pragma unroll
    for (int ob = 0; ob < 2; ++ob)
#pragma unroll
        for (int pb = 0; pb < 4; ++pb) acc[ob][pb] = (f32x4){0.f, 0.f, 0.f, 0.f};

    const float* offb = offout + (size_t)b * 27 * HW_ + ho * 64 + pxa;
    const u32* xb = xtu + (size_t)b * HW_ * CU_;

#pragma unroll 1
    for (int n = 0; n < 9; ++n) {
        // --- preload W fragments for this tap ---
        uint4 wf[2][4];
#pragma unroll
        for (int ob = 0; ob < 2; ++ob)
#pragma unroll
            for (int ks = 0; ks < 4; ++ks)
                wf[ob][ks] = *(const uint4*)(wtu + (size_t)(o0 + ob * 16 + l15) * 576
                                             + n * 64 + ks * 16 + lhi * 4);
        // --- A: per-lane pixel params ---
        float dy = offb[(size_t)(2 * n) * HW_];
        float dx = offb[(size_t)(2 * n + 1) * HW_];
        float m  = offb[(size_t)(18 + n) * HW_];
        float ys = (float)(ho + n / 3 - 1) + dy;
        float xs = (float)(pxa + n % 3 - 1) + dx;
        float y0f = floorf(ys), x0f = floorf(xs);
        float fy = ys - y0f, fx = xs - x0f;
        int y0 = (int)y0f, x0 = (int)x0f;
        bool vy0 = (unsigned)y0 < 64u, vy1 = (unsigned)(y0 + 1) < 64u;
        bool vx0 = (unsigned)x0 < 64u, vx1 = (unsigned)(x0 + 1) < 64u;
        float w00 = (vy0 && vx0) ? (1.f - fy) * (1.f - fx) * m : 0.f;
        float w01 = (vy0 && vx1) ? (1.f - fy) * fx * m : 0.f;
        float w10 = (vy1 && vx0) ? fy * (1.f - fx) * m : 0.f;
        float w11 = (vy1 && vx1) ? fy * fx * m : 0.f;
        int y0c = min(max(y0, 0), 63), y1c = min(max(y0 + 1, 0), 63);
        int x0c = min(max(x0, 0), 63), x1c = min(max(x0 + 1, 0), 63);
        int a00 = (y0c << 12) + (x0c << 6);
        int a01 = (y0c << 12) + (x1c << 6);
        int a10 = (y1c << 12) + (x0c << 6);
        int a11 = (y1c << 12) + (x1c << 6);
        // --- B: coalesced gather + blend, 2 groups of 8 px ---
        int buf = n & 1;
#pragma unroll 1
        for (int g = 0; g < 2; ++g) {
            u32 ld[8][4];
#pragma unroll
            for (int j2 = 0; j2 < 8; ++j2) {
                int jj = (g << 3) + j2;
                ld[j2][0] = xb[__builtin_amdgcn_readlane(a00, jj) + lane];
                ld[j2][1] = xb[__builtin_amdgcn_readlane(a01, jj) + lane];
                ld[j2][2] = xb[__builtin_amdgcn_readlane(a10, jj) + lane];
                ld[j2][3] = xb[__builtin_amdgcn_readlane(a11, jj) + lane];
            }
#pragma unroll
            for (int j2 = 0; j2 < 8; ++j2) {
                int jj = (g << 3) + j2;
                float s0 = rlf(w00, jj), s1 = rlf(w01, jj);
                float s2 = rlf(w10, jj), s3 = rlf(w11, jj);
                float slo = s0 * blo(ld[j2][0]) + s1 * blo(ld[j2][1])
                          + s2 * blo(ld[j2][2]) + s3 * blo(ld[j2][3]);
                float shi = s0 * bhi(ld[j2][0]) + s1 * bhi(ld[j2][1])
                          + s2 * bhi(ld[j2][2]) + s3 * bhi(ld[j2][3]);
                S[buf][(w << 4) + jj][lane] = pk(slo, shi);
            }
        }
        __syncthreads();
        // --- C: MFMA D[o][px] += W_tap * S_tap^T ---
#pragma unroll
        for (int ks = 0; ks < 4; ++ks) {
            U16 sf[4];
#pragma unroll
            for (int pb = 0; pb < 4; ++pb)
                sf[pb].u = *(const uint4*)&S[buf][pb * 16 + l15][(ks * 4 + lhi) << 2];
#pragma unroll
            for (int ob = 0; ob < 2; ++ob) {
                U16 af; af.u = wf[ob][ks];
#pragma unroll
                for (int pb = 0; pb < 4; ++pb)
                    acc[ob][pb] = __builtin_amdgcn_mfma_f32_16x16x32_bf16(
                        af.h, sf[pb].h, acc[ob][pb], 0, 0, 0);
            }
        }
    }
    // --- epilogue: o = o0+ob*16+lhi*4+r, px = pb*16+l15 ---
    float* ob_base = out + (size_t)b * 128 * HW_ + ho * 64;
#pragma unroll
    for (int ob = 0; ob < 2; ++ob)
#pragma unroll
        for (int r = 0; r < 4; ++r) {
            int o = o0 + ob * 16 + lhi * 4 + r;
            float bv = bias[o];
#pragma unroll
            for (int pb = 0; pb < 4; ++pb)
                ob_base[(size_t)o * HW_ + pb * 16 + l15] = acc[ob][pb][r] + bv;
        }
}

extern "C" void kernel_launch(void* const* d_in, const int* in_sizes, int n_in,
                              void* d_out, int out_size, void* d_ws, size_t ws_size,
                              hipStream_t stream) {
    const float* x      = (const float*)d_in[0];
    const float* weight = (const float*)d_in[1];
    const float* bias   = (const float*)d_in[2];
    const float* off_w  = (const float*)d_in[3];
    const float* off_b  = (const float*)d_in[4];
    float* out = (float*)d_out;

    u32*   xtu    = (u32*)d_ws;
    float* offout = (float*)(xtu + (size_t)B_ * HW_ * CU_);
    u32*   wtu    = (u32*)(offout + (size_t)B_ * 27 * HW_);
    u32*   woffu  = wtu + 73728;

    hipLaunchKernelGGL(k_transpose, dim3(2048), dim3(256), 0, stream, x, xtu);
    hipLaunchKernelGGL(k_prep, dim3((73728 + 18432 + 255) / 256), dim3(256), 0, stream,
                       weight, off_w, wtu, woffu);
    hipLaunchKernelGGL(k_offconv, dim3(1024), dim3(256), 0, stream, xtu, woffu, off_b, offout);
    hipLaunchKernelGGL(k_fused, dim3(1024), dim3(256), 0, stream, xtu, offout, wtu, bias, out);
}

// Round 5
// 119.987 us; speedup vs baseline: 11.4826x; 1.0898x over previous
//
#include <hip/hip_runtime.h>
#include <hip/hip_fp16.h>

// DCNv2 R5: fp16 everywhere, packed-half2 bilinear blend.
//   k_transpose: x NCHW f32 -> NHWC fp16 pairs (xtu)
//   k_prep:      wtu[o][n*64+cu], woffu[32][tap*64+cu] fp16 pairs
//   k_offconv:   offset/mask conv via mfma_f32_16x16x32_f16 (R3 structure)
//   k_fused:     phase A: per-lane px params (4 masked weights packed (w,w), 4 clamped addrs)
//                phase B: readlane->SGPR broadcast, coalesced lane=channel loads,
//                         blend with 4x v_pk_fma_f16 per px, write S
//                phase C: D[o][px] += W*S^T via mfma_f32_16x16x32_f16
//   S double-buffered [2][64][68], one barrier per tap. XCD-chunked block swizzle.

typedef unsigned int u32;
typedef __attribute__((ext_vector_type(8))) _Float16 f16x8;
typedef __attribute__((ext_vector_type(4))) float f32x4;

union U16 { uint4 u; f16x8 h; };
union H2U { __half2 h2; u32 u; };

static __device__ __forceinline__ u32 pkh(float a, float b) {
    H2U c; c.h2 = __float22half2_rn(make_float2(a, b)); return c.u;
}
static __device__ __forceinline__ u32 pkw(float w) {
    __half h = __float2half_rn(w);
    H2U c; c.h2 = __half2(h, h); return c.u;
}
static __device__ __forceinline__ u32 hfma2u(u32 a, u32 w, u32 acc) {
    H2U x, y, z; x.u = a; y.u = w; z.u = acc;
    z.h2 = __hfma2(x.h2, y.h2, z.h2); return z.u;
}

#define B_   16
#define HW_  4096
#define CU_  64          // 128 ch = 64 fp16-pair words

// ---------------- kernel 1: NCHW f32 -> NHWC fp16 ----------------
__global__ __launch_bounds__(256) void k_transpose(const float* __restrict__ x,
                                                   u32* __restrict__ xtu) {
    __shared__ float tile[32][129];
    int blk = blockIdx.x, t = threadIdx.x;
    int b = blk >> 7, hw0 = (blk & 127) << 5;
    int hwl = t & 31, cg = t >> 5;
    const float* src = x + (size_t)b * 128 * HW_ + hw0 + hwl;
#pragma unroll
    for (int i = 0; i < 16; ++i) { int c = cg + (i << 3); tile[hwl][c] = src[(size_t)c * HW_]; }
    __syncthreads();
    u32* dst = xtu + ((size_t)b * HW_ + hw0) * CU_;
    int u = t & 63, hq = t >> 6;
#pragma unroll
    for (int j = 0; j < 8; ++j) {
        int hw = (hq << 3) + j;
        dst[(size_t)hw * CU_ + u] = pkh(tile[hw][2 * u], tile[hw][2 * u + 1]);
    }
}

// ---------------- kernel 2: weight prep ----------------
__global__ __launch_bounds__(256) void k_prep(const float* __restrict__ weight,
                                              const float* __restrict__ off_w,
                                              u32* __restrict__ wtu,
                                              u32* __restrict__ woffu) {
    int idx = blockIdx.x * 256 + threadIdx.x;
    if (idx < 73728) {
        int o = idx / 576, r = idx % 576;
        int n = r / 64, cu = r % 64, c = cu * 2;
        float a = weight[((size_t)(o * 128 + c)) * 9 + n];
        float b = weight[((size_t)(o * 128 + c + 1)) * 9 + n];
        wtu[idx] = pkh(a, b);
    } else if (idx < 73728 + 18432) {
        int k = idx - 73728;
        int o = k / 576, r = k % 576;
        int tap = r / 64, cu = r % 64, c = cu * 2;
        u32 v = 0u;
        if (o < 27) {
            float a = off_w[((size_t)(o * 128 + c)) * 9 + tap];
            float b = off_w[((size_t)(o * 128 + c + 1)) * 9 + tap];
            v = pkh(a, b);
        }
        woffu[k] = v;
    }
}

// ---------------- kernel 3: offset/mask conv via MFMA ----------------
__global__ __launch_bounds__(256) void k_offconv(const u32* __restrict__ xtu,
                                                 const u32* __restrict__ woffu,
                                                 const float* __restrict__ off_b,
                                                 float* __restrict__ offout) {
    __shared__ __align__(16) u32 S[3][64][64];
    int blk = ((blockIdx.x & 7) << 7) + (blockIdx.x >> 3);   // XCD-chunked
    int t = threadIdx.x;
    int b = blk >> 6, ho = blk & 63;
    const u32* xb = xtu + (size_t)b * HW_ * CU_;
    const uint4 z4 = {0u, 0u, 0u, 0u};
#pragma unroll
    for (int i = 0; i < 12; ++i) {
        int li = t + (i << 8);
        int r = li >> 10, rem = li & 1023;
        int px = rem >> 4, ch = rem & 15;
        int yy = ho + r - 1;
        uint4 v = ((unsigned)yy < 64u) ? *(const uint4*)(xb + ((yy << 6) + px) * CU_ + (ch << 2)) : z4;
        *(uint4*)&S[r][px][(ch ^ (px & 7)) << 2] = v;
    }
    __syncthreads();
    int lane = t & 63, w = t >> 6, l15 = lane & 15, lhi = lane >> 4;
    int ob = w >> 1, pb0 = (w & 1) << 1;
    f32x4 acc[2];
    acc[0] = (f32x4){0.f, 0.f, 0.f, 0.f};
    acc[1] = (f32x4){0.f, 0.f, 0.f, 0.f};
#pragma unroll 1
    for (int tap = 0; tap < 9; ++tap) {
        int ky = tap / 3, kx = tap % 3;
        int yy = ho + ky - 1;
        if ((unsigned)yy >= 64u) continue;
        U16 af[4];
#pragma unroll
        for (int ks = 0; ks < 4; ++ks)
            af[ks].u = *(const uint4*)(woffu + (size_t)(ob * 16 + l15) * 576
                                       + tap * 64 + ks * 16 + lhi * 4);
#pragma unroll
        for (int pp = 0; pp < 2; ++pp) {
            int pr = ((pb0 + pp) << 4) + l15;
            int pxs = pr + kx - 1;
            bool v = (unsigned)pxs < 64u;
            int pxc = v ? pxs : 0;
#pragma unroll
            for (int ks = 0; ks < 4; ++ks) {
                U16 sf;
                sf.u = v ? *(const uint4*)&S[ky][pxc][((ks * 4 + lhi) ^ (pxc & 7)) << 2] : z4;
                acc[pp] = __builtin_amdgcn_mfma_f32_16x16x32_f16(af[ks].h, sf.h, acc[pp], 0, 0, 0);
            }
        }
    }
    float* dst = offout + (size_t)b * 27 * HW_ + (ho << 6);
#pragma unroll
    for (int pp = 0; pp < 2; ++pp)
#pragma unroll
        for (int r = 0; r < 4; ++r) {
            int o = ob * 16 + lhi * 4 + r;
            if (o < 27) {
                float s = acc[pp][r] + off_b[o];
                if (o >= 18) s = 1.f / (1.f + __expf(-s));
                dst[(size_t)o * HW_ + ((pb0 + pp) << 4) + l15] = s;
            }
        }
}

// ---------------- kernel 4: fused sample + MFMA, packed-f16 blend ----------------
__global__ __launch_bounds__(256, 4) void k_fused(const u32* __restrict__ xtu,
                                                  const float* __restrict__ offout,
                                                  const u32* __restrict__ wtu,
                                                  const float* __restrict__ bias,
                                                  float* __restrict__ out) {
    __shared__ __align__(16) u32 S[2][64][68];   // dbuf, 68-word rows
    int blk = ((blockIdx.x & 7) << 7) + (blockIdx.x >> 3);   // XCD-chunked
    int t = threadIdx.x;
    int b = blk >> 6, ho = blk & 63;
    int w = t >> 6, lane = t & 63, l15 = lane & 15, lhi = lane >> 4;
    int o0 = w * 32;
    int pxa = (w << 4) + l15;        // pixel this lane computes params for

    f32x4 acc[2][4];
#pragma unroll
    for (int ob = 0; ob < 2; ++ob)
#pragma unroll
        for (int pb = 0; pb < 4; ++pb) acc[ob][pb] = (f32x4){0.f, 0.f, 0.f, 0.f};

    const float* offb = offout + (size_t)b * 27 * HW_ + ho * 64 + pxa;
    const u32* xb = xtu + (size_t)b * HW_ * CU_;

#pragma unroll 1
    for (int n = 0; n < 9; ++n) {
        // --- preload W fragments for this tap ---
        uint4 wf[2][4];
#pragma unroll
        for (int ob = 0; ob < 2; ++ob)
#pragma unroll
            for (int ks = 0; ks < 4; ++ks)
                wf[ob][ks] = *(const uint4*)(wtu + (size_t)(o0 + ob * 16 + l15) * 576
                                             + n * 64 + ks * 16 + lhi * 4);
        // --- A: per-lane pixel params ---
        float dy = offb[(size_t)(2 * n) * HW_];
        float dx = offb[(size_t)(2 * n + 1) * HW_];
        float m  = offb[(size_t)(18 + n) * HW_];
        float ys = (float)(ho + n / 3 - 1) + dy;
        float xs = (float)(pxa + n % 3 - 1) + dx;
        float y0f = floorf(ys), x0f = floorf(xs);
        float fy = ys - y0f, fx = xs - x0f;
        int y0 = (int)y0f, x0 = (int)x0f;
        bool vy0 = (unsigned)y0 < 64u, vy1 = (unsigned)(y0 + 1) < 64u;
        bool vx0 = (unsigned)x0 < 64u, vx1 = (unsigned)(x0 + 1) < 64u;
        u32 w00 = pkw((vy0 && vx0) ? (1.f - fy) * (1.f - fx) * m : 0.f);
        u32 w01 = pkw((vy0 && vx1) ? (1.f - fy) * fx * m : 0.f);
        u32 w10 = pkw((vy1 && vx0) ? fy * (1.f - fx) * m : 0.f);
        u32 w11 = pkw((vy1 && vx1) ? fy * fx * m : 0.f);
        int y0c = min(max(y0, 0), 63), y1c = min(max(y0 + 1, 0), 63);
        int x0c = min(max(x0, 0), 63), x1c = min(max(x0 + 1, 0), 63);
        int a00 = (y0c << 12) + (x0c << 6);
        int a01 = (y0c << 12) + (x1c << 6);
        int a10 = (y1c << 12) + (x0c << 6);
        int a11 = (y1c << 12) + (x1c << 6);
        // --- B: coalesced gather + packed-f16 blend, 2 groups of 8 px ---
        int buf = n & 1;
#pragma unroll 1
        for (int g = 0; g < 2; ++g) {
            u32 ld[8][4];
#pragma unroll
            for (int j2 = 0; j2 < 8; ++j2) {
                int jj = (g << 3) + j2;
                ld[j2][0] = xb[__builtin_amdgcn_readlane(a00, jj) + lane];
                ld[j2][1] = xb[__builtin_amdgcn_readlane(a01, jj) + lane];
                ld[j2][2] = xb[__builtin_amdgcn_readlane(a10, jj) + lane];
                ld[j2][3] = xb[__builtin_amdgcn_readlane(a11, jj) + lane];
            }
#pragma unroll
            for (int j2 = 0; j2 < 8; ++j2) {
                int jj = (g << 3) + j2;
                u32 s0 = (u32)__builtin_amdgcn_readlane((int)w00, jj);
                u32 s1 = (u32)__builtin_amdgcn_readlane((int)w01, jj);
                u32 s2 = (u32)__builtin_amdgcn_readlane((int)w10, jj);
                u32 s3 = (u32)__builtin_amdgcn_readlane((int)w11, jj);
                u32 a = hfma2u(ld[j2][0], s0, 0u);
                a = hfma2u(ld[j2][1], s1, a);
                a = hfma2u(ld[j2][2], s2, a);
                a = hfma2u(ld[j2][3], s3, a);
                S[buf][(w << 4) + jj][lane] = a;
            }
        }
        __syncthreads();
        // --- C: MFMA D[o][px] += W_tap * S_tap^T ---
#pragma unroll
        for (int ks = 0; ks < 4; ++ks) {
            U16 sf[4];
#pragma unroll
            for (int pb = 0; pb < 4; ++pb)
                sf[pb].u = *(const uint4*)&S[buf][pb * 16 + l15][(ks * 4 + lhi) << 2];
#pragma unroll
            for (int ob = 0; ob < 2; ++ob) {
                U16 af; af.u = wf[ob][ks];
#pragma unroll
                for (int pb = 0; pb < 4; ++pb)
                    acc[ob][pb] = __builtin_amdgcn_mfma_f32_16x16x32_f16(
                        af.h, sf[pb].h, acc[ob][pb], 0, 0, 0);
            }
        }
    }
    // --- epilogue: o = o0+ob*16+lhi*4+r, px = pb*16+l15 ---
    float* ob_base = out + (size_t)b * 128 * HW_ + ho * 64;
#pragma unroll
    for (int ob = 0; ob < 2; ++ob)
#pragma unroll
        for (int r = 0; r < 4; ++r) {
            int o = o0 + ob * 16 + lhi * 4 + r;
            float bv = bias[o];
#pragma unroll
            for (int pb = 0; pb < 4; ++pb)
                ob_base[(size_t)o * HW_ + pb * 16 + l15] = acc[ob][pb][r] + bv;
        }
}

extern "C" void kernel_launch(void* const* d_in, const int* in_sizes, int n_in,
                              void* d_out, int out_size, void* d_ws, size_t ws_size,
                              hipStream_t stream) {
    const float* x      = (const float*)d_in[0];
    const float* weight = (const float*)d_in[1];
    const float* bias   = (const float*)d_in[2];
    const float* off_w  = (const float*)d_in[3];
    const float* off_b  = (const float*)d_in[4];
    float* out = (float*)d_out;

    u32*   xtu    = (u32*)d_ws;
    float* offout = (float*)(xtu + (size_t)B_ * HW_ * CU_);
    u32*   wtu    = (u32*)(offout + (size_t)B_ * 27 * HW_);
    u32*   woffu  = wtu + 73728;

    hipLaunchKernelGGL(k_transpose, dim3(2048), dim3(256), 0, stream, x, xtu);
    hipLaunchKernelGGL(k_prep, dim3((73728 + 18432 + 255) / 256), dim3(256), 0, stream,
                       weight, off_w, wtu, woffu);
    hipLaunchKernelGGL(k_offconv, dim3(1024), dim3(256), 0, stream, xtu, woffu, off_b, offout);
    hipLaunchKernelGGL(k_fused, dim3(1024), dim3(256), 0, stream, xtu, offout, wtu, bias, out);
}